// Round 3
// baseline (4700.286 us; speedup 1.0000x reference)
//
#include <hip/hip_runtime.h>

#define B_ 2048
#define T_ 128
#define S_ 256
#define V_ 29

typedef _Float16 h2_t __attribute__((ext_vector_type(2)));
typedef __fp16 hh2 __attribute__((ext_vector_type(2)));

__device__ __forceinline__ unsigned packh(float a, float b) {
    h2_t p;
    p.x = (_Float16)a;
    p.y = (_Float16)b;
    return __builtin_bit_cast(unsigned, p);
}

// fp32 accumulate of a 2-term fp16 dot. Prefer the single-instruction
// v_dot2_f32_f16; fall back to v_fma_mix_f32 pattern.
__device__ __forceinline__ float dot2(unsigned a, unsigned b, float c) {
#if __has_builtin(__builtin_amdgcn_fdot2)
    return __builtin_amdgcn_fdot2(__builtin_bit_cast(hh2, a),
                                  __builtin_bit_cast(hh2, b), c, false);
#else
    h2_t ah = __builtin_bit_cast(h2_t, a);
    h2_t bh = __builtin_bit_cast(h2_t, b);
    c = fmaf((float)ah.x, (float)bh.x, c);
    c = fmaf((float)ah.y, (float)bh.y, c);
    return c;
#endif
}

// ---------------------------------------------------------------------------
// Precompute (1 block, 256 threads). Thread g owns gate row g = q*64 + j
// (q = gate block i/f/g/o, j = hidden index). The decoder thread that will
// consume row g is tidg = (j>>4)*64 + (j&15)*4 + q  (quad-of-lanes layout).
//   ws[0 .. 29*256)          gate_embP[v][tidg] = b_ih[g]+b_hh[g]+emb[v]·W_ih[g,0:32]
//   ws[29*256 .. +256*128)   wcatP[tidg][0:64]=W_ih[g][32:96], [64:128]=W_hh[g]
// ---------------------------------------------------------------------------
__global__ __launch_bounds__(256) void precompute_kernel(
    const float* __restrict__ emb_table, const float* __restrict__ W_ih,
    const float* __restrict__ W_hh, const float* __restrict__ b_ih,
    const float* __restrict__ b_hh, float* __restrict__ ws)
{
    const int g = threadIdx.x;
    const int q = g >> 6, j = g & 63;
    const int tidg = (j >> 4) * 64 + (j & 15) * 4 + q;

    float wemb[32];
#pragma unroll
    for (int e = 0; e < 32; ++e) wemb[e] = W_ih[g * 96 + e];
    const float bb = b_ih[g] + b_hh[g];
    for (int v = 0; v < V_; ++v) {
        float acc = bb;
#pragma unroll
        for (int e = 0; e < 32; ++e) acc = fmaf(emb_table[v * 32 + e], wemb[e], acc);
        ws[v * 256 + tidg] = acc;
    }
    float* wcatP = ws + V_ * 256;
#pragma unroll
    for (int k = 0; k < 64; ++k) wcatP[tidg * 128 + k] = W_ih[g * 96 + 32 + k];
#pragma unroll
    for (int k = 0; k < 64; ++k) wcatP[tidg * 128 + 64 + k] = W_hh[g * 64 + k];
}

// ---------------------------------------------------------------------------
// Main decoder: 1 block = 1 batch row, 256 threads, T=128 steps, 3 barriers/step.
//  - enc working sets held in REGISTERS (ereg: P1 row, e2reg: P2 quads) —
//    no enc LDS array at all; LDS ~5.9 KB.
//  - softmax denominator folded into P2's reduce (5th component) — P1 has
//    no cross-lane ops.
//  - logits (P5) deferred one step, overlapped with next P1; out-write after BA.
// ---------------------------------------------------------------------------
__global__ __launch_bounds__(256, 3) void decoder_kernel(
    const int* __restrict__ y, const float* __restrict__ h0,
    const float* __restrict__ c0, const float* __restrict__ enc,
    const float* __restrict__ fc_W, const float* __restrict__ fc_b,
    const float* __restrict__ ws, float* __restrict__ out)
{
    __shared__ float4 attnP[16 * 17];                 // padded e-values (4.25 KB)
    __shared__ __align__(16) _Float16 ctxh[64];       // context (fp16)
    __shared__ __align__(16) _Float16 h2buf[2][64];   // double-buffered h (fp16)
    __shared__ float red[128];                        // logits reduction
    __shared__ int yrow[T_];

    const int tid = threadIdx.x;
    const int b = blockIdx.x;
    const int wid = tid >> 6;
    const int lane = tid & 63;

    // --- gate row registers (permuted ownership: quad lane qg, hidden jg) ---
    const int qg = lane & 3;
    const int jg = wid * 16 + (lane >> 2);
    const float* wcatP = ws + V_ * 256;
    uint2 wh[32];                                     // 128 fp16 weights = 64 VGPRs
    {
        const float4* wrow = (const float4*)(wcatP + tid * 128);
#pragma unroll
        for (int k = 0; k < 32; ++k) {
            float4 wv = wrow[k];
            wh[k].x = packh(wv.x, wv.y);
            wh[k].y = packh(wv.z, wv.w);
        }
    }

    // --- fc registers: thread (v = tid&31, jj = tid>>5) covers 16 k's ---
    const int v = tid & 31;
    const int jj = tid >> 5;
    uint2 fcwh[4];
    float fcb = 0.f;
    if (v < V_) {
#pragma unroll
        for (int k = 0; k < 4; ++k) {
            float4 wv = ((const float4*)(fc_W + v * 128 + jj * 16))[k];
            fcwh[k].x = packh(wv.x, wv.y);
            fcwh[k].y = packh(wv.z, wv.w);
        }
        fcb = fc_b[v];
    } else {
#pragma unroll
        for (int k = 0; k < 4; ++k) { fcwh[k].x = 0u; fcwh[k].y = 0u; }
    }

    // context-pass lane mapping
    const int hq = lane >> 4;           // 0..3
    const int sq = lane & 15;           // s-chunk of 16
    const int hqg = wid * 4 + hq;       // global h-quad 0..15

    // --- enc working sets -> registers (fixed addresses for the whole loop) ---
    const float* encb = enc + (size_t)b * S_ * 64;
    uint2 ereg[16];                     // P1: own row s = tid, dims 4i..4i+3
    {
        const float4* rowp = (const float4*)(encb + tid * 64);
#pragma unroll
        for (int i = 0; i < 16; ++i) {
            float4 e = rowp[i];
            ereg[i].x = packh(e.x, e.y);
            ereg[i].y = packh(e.z, e.w);
        }
    }
    uint2 e2reg[16];                    // P2: quad (s = sq*16+4k+j2, dims hqg*4..)
#pragma unroll
    for (int k = 0; k < 4; ++k) {
#pragma unroll
        for (int j2 = 0; j2 < 4; ++j2) {
            int s = sq * 16 + 4 * k + j2;
            float4 e = *(const float4*)(encb + s * 64 + hqg * 4);
            e2reg[4 * k + j2].x = packh(e.x, e.y);
            e2reg[4 * k + j2].y = packh(e.z, e.w);
        }
    }

    if (tid < 64) h2buf[0][tid] = (_Float16)h0[b * 64 + tid];
    float creg = c0[b * 64 + jg];                     // c state lives in a register
    if (tid < T_) yrow[tid] = y[b * T_ + tid];
    __syncthreads();

    float* attnPf = (float*)attnP;

    for (int t = 0; t < T_; ++t) {
        const int cur = t & 1, nxt = cur ^ 1;
        const float ge = ws[yrow[t] * 256 + tid];     // gate_embP, L1/L2-hot

        // ---- Phase A: P5 logits for step t-1 (overlapped) + P1 scores for t
        if (t) {
            const _Float16* basep = (jj < 4) ? &h2buf[cur][16 * jj] : &ctxh[16 * jj - 64];
            float a0 = 0.f, a1 = 0.f;
#pragma unroll
            for (int k = 0; k < 4; ++k) {
                uint2 c4 = *(const uint2*)(basep + 4 * k);
                a0 = dot2(fcwh[k].x, c4.x, a0);
                a1 = dot2(fcwh[k].y, c4.y, a1);
            }
            float acc = a0 + a1;
            acc += __shfl_xor(acc, 32);               // fold jj pairs
            if ((tid & 32) == 0) red[wid * 32 + v] = acc;
        }
        {
            float sc0 = 0.f, sc1 = 0.f, sc2 = 0.f, sc3 = 0.f;
#pragma unroll
            for (int i = 0; i < 16; i += 2) {
                uint2 ha = *(const uint2*)&h2buf[cur][4 * i];
                uint2 hb = *(const uint2*)&h2buf[cur][4 * i + 4];
                sc0 = dot2(ereg[i].x, ha.x, sc0);
                sc1 = dot2(ereg[i].y, ha.y, sc1);
                sc2 = dot2(ereg[i + 1].x, hb.x, sc2);
                sc3 = dot2(ereg[i + 1].y, hb.y, sc3);
            }
            float sc = (sc0 + sc1) + (sc2 + sc3);
            float ex = __expf(fminf(sc, 60.f));
            attnPf[(tid >> 4) * 68 + (tid & 15)] = ex;
        }
        __syncthreads();  // BA

        // out-write for step t-1 (red stable until next Phase A, 2 barriers away)
        if (t && tid < V_) {
            float r = red[tid] + red[32 + tid] + red[64 + tid] + red[96 + tid] + fcb;
            out[((size_t)b * T_ + (t - 1)) * V_ + tid] = r;
        }

        // ---- P2: context + softmax denominator (5-component reduce over sq)
        {
            float4 acc = make_float4(0.f, 0.f, 0.f, 0.f);
            float es = 0.f;
#pragma unroll
            for (int k = 0; k < 4; ++k) {
                float4 a4 = attnP[sq * 17 + k];
                es += (a4.x + a4.y) + (a4.z + a4.w);
#pragma unroll
                for (int j2 = 0; j2 < 4; ++j2) {
                    uint2 e = e2reg[4 * k + j2];
                    h2_t e0 = __builtin_bit_cast(h2_t, e.x);
                    h2_t e1 = __builtin_bit_cast(h2_t, e.y);
                    float aw = (&a4.x)[j2];
                    acc.x = fmaf((float)e0.x, aw, acc.x);
                    acc.y = fmaf((float)e0.y, aw, acc.y);
                    acc.z = fmaf((float)e1.x, aw, acc.z);
                    acc.w = fmaf((float)e1.y, aw, acc.w);
                }
            }
#pragma unroll
            for (int off = 1; off <= 8; off <<= 1) {
                acc.x += __shfl_xor(acc.x, off);
                acc.y += __shfl_xor(acc.y, off);
                acc.z += __shfl_xor(acc.z, off);
                acc.w += __shfl_xor(acc.w, off);
                es    += __shfl_xor(es, off);
            }
            if (sq == 0) {
                const float inv = __builtin_amdgcn_rcpf(es);
                uint2 r;
                r.x = packh(acc.x * inv, acc.y * inv);
                r.y = packh(acc.z * inv, acc.w * inv);
                *(uint2*)&ctxh[4 * hqg] = r;
            }
        }
        __syncthreads();  // BB

        // ---- P3: gate dot (row qg*64+jg) + quad-shuffle LSTM
        {
            float g0 = ge, g1 = 0.f, g2 = 0.f, g3 = 0.f;
#pragma unroll
            for (int k = 0; k < 16; k += 2) {
                uint2 xa = *(const uint2*)&ctxh[4 * k];
                uint2 xb = *(const uint2*)&ctxh[4 * (k + 1)];
                g0 = dot2(wh[k].x, xa.x, g0);
                g1 = dot2(wh[k].y, xa.y, g1);
                g2 = dot2(wh[k + 1].x, xb.x, g2);
                g3 = dot2(wh[k + 1].y, xb.y, g3);
            }
#pragma unroll
            for (int k = 0; k < 16; k += 2) {
                uint2 xa = *(const uint2*)&h2buf[cur][4 * k];
                uint2 xb = *(const uint2*)&h2buf[cur][4 * (k + 1)];
                g0 = dot2(wh[16 + k].x, xa.x, g0);
                g1 = dot2(wh[16 + k].y, xa.y, g1);
                g2 = dot2(wh[17 + k].x, xb.x, g2);
                g3 = dot2(wh[17 + k].y, xb.y, g3);
            }
            float gacc = (g0 + g1) + (g2 + g3);
            const float v1 = __shfl_xor(gacc, 1);
            const float v2 = __shfl_xor(gacc, 2);
            const float v3 = __shfl_xor(gacc, 3);
            // value of gate block p is [gacc,v1,v2,v3][p ^ qg]
            const bool b1 = qg & 1, b2 = qg & 2;
            const float gi = b2 ? (b1 ? v3 : v2) : (b1 ? v1 : gacc);
            const float gf = b2 ? (b1 ? v2 : v3) : (b1 ? gacc : v1);
            const float gg = b2 ? (b1 ? v1 : gacc) : (b1 ? v3 : v2);
            const float go = b2 ? (b1 ? gacc : v1) : (b1 ? v2 : v3);
            const float si = __builtin_amdgcn_rcpf(1.f + __expf(-gi));
            const float sf = __builtin_amdgcn_rcpf(1.f + __expf(-gf));
            const float so = __builtin_amdgcn_rcpf(1.f + __expf(-go));
            const float tg = 1.f - 2.f * __builtin_amdgcn_rcpf(__expf(2.f * gg) + 1.f);
            creg = sf * creg + si * tg;
            const float hn = so * (1.f - 2.f * __builtin_amdgcn_rcpf(__expf(2.f * creg) + 1.f));
            if (qg == 0) h2buf[nxt][jg] = (_Float16)hn;
        }
        __syncthreads();  // BD
    }

    // ---- tail: logits for the last step (h_new lives in h2buf[T_ & 1] = [0])
    {
        const _Float16* basep = (jj < 4) ? &h2buf[0][16 * jj] : &ctxh[16 * jj - 64];
        float a0 = 0.f, a1 = 0.f;
#pragma unroll
        for (int k = 0; k < 4; ++k) {
            uint2 c4 = *(const uint2*)(basep + 4 * k);
            a0 = dot2(fcwh[k].x, c4.x, a0);
            a1 = dot2(fcwh[k].y, c4.y, a1);
        }
        float acc = a0 + a1;
        acc += __shfl_xor(acc, 32);
        if ((tid & 32) == 0) red[wid * 32 + v] = acc;
    }
    __syncthreads();
    if (tid < V_) {
        float r = red[tid] + red[32 + tid] + red[64 + tid] + red[96 + tid] + fcb;
        out[((size_t)b * T_ + (T_ - 1)) * V_ + tid] = r;
    }
}

extern "C" void kernel_launch(void* const* d_in, const int* in_sizes, int n_in,
                              void* d_out, int out_size, void* d_ws, size_t ws_size,
                              hipStream_t stream)
{
    const int*   y    = (const int*)  d_in[0];
    const float* h0   = (const float*)d_in[1];
    const float* c0   = (const float*)d_in[2];
    const float* enc  = (const float*)d_in[3];
    const float* emb  = (const float*)d_in[4];
    const float* W_ih = (const float*)d_in[5];
    const float* W_hh = (const float*)d_in[6];
    const float* b_ih = (const float*)d_in[7];
    const float* b_hh = (const float*)d_in[8];
    const float* fc_W = (const float*)d_in[9];
    const float* fc_b = (const float*)d_in[10];
    float* ws  = (float*)d_ws;   // needs (29*256 + 256*128)*4 = 157 KB
    float* out = (float*)d_out;

    precompute_kernel<<<1, 256, 0, stream>>>(emb, W_ih, W_hh, b_ih, b_hh, ws);
    decoder_kernel<<<B_, 256, 0, stream>>>(y, h0, c0, enc, fc_W, fc_b, ws, out);
}

// Round 5
// 4075.860 us; speedup vs baseline: 1.1532x; 1.1532x over previous
//
#include <hip/hip_runtime.h>

#define B_ 2048
#define T_ 128
#define S_ 256
#define V_ 29

typedef _Float16 h2_t __attribute__((ext_vector_type(2)));
typedef __fp16 hh2 __attribute__((ext_vector_type(2)));

__device__ __forceinline__ unsigned packh(float a, float b) {
    h2_t p;
    p.x = (_Float16)a;
    p.y = (_Float16)b;
    return __builtin_bit_cast(unsigned, p);
}

// fp32 accumulate of a 2-term fp16 dot (v_dot2_f32_f16 on gfx950).
__device__ __forceinline__ float dot2(unsigned a, unsigned b, float c) {
#if __has_builtin(__builtin_amdgcn_fdot2)
    return __builtin_amdgcn_fdot2(__builtin_bit_cast(hh2, a),
                                  __builtin_bit_cast(hh2, b), c, false);
#else
    h2_t ah = __builtin_bit_cast(h2_t, a);
    h2_t bh = __builtin_bit_cast(h2_t, b);
    c = fmaf((float)ah.x, (float)bh.x, c);
    c = fmaf((float)ah.y, (float)bh.y, c);
    return c;
#endif
}

// Swizzled index for enc quad (s, h4) — quad is 4×fp16 = 8 B (uint2).
__device__ __forceinline__ int enc_idx(int s, int h4) {
    return s * 16 + ((h4 + s + (s >> 4)) & 15);
}

// ---------------------------------------------------------------------------
// Precompute (1 block, 256 threads). Thread g owns gate row g = q*64 + j.
// Consumer thread: tidg = (j>>4)*64 + (j&15)*4 + q (quad-of-lanes layout).
//   ws[0 .. 29*256)          gate_embP[v][tidg] = b_ih[g]+b_hh[g]+emb[v]·W_ih[g,0:32]
//   ws[29*256 .. +256*128)   wcatP[tidg][0:64]=W_ih[g][32:96] (ctx), [64:128]=W_hh[g] (h)
// ---------------------------------------------------------------------------
__global__ __launch_bounds__(256) void precompute_kernel(
    const float* __restrict__ emb_table, const float* __restrict__ W_ih,
    const float* __restrict__ W_hh, const float* __restrict__ b_ih,
    const float* __restrict__ b_hh, float* __restrict__ ws)
{
    const int g = threadIdx.x;
    const int q = g >> 6, j = g & 63;
    const int tidg = (j >> 4) * 64 + (j & 15) * 4 + q;

    float wemb[32];
#pragma unroll
    for (int e = 0; e < 32; ++e) wemb[e] = W_ih[g * 96 + e];
    const float bb = b_ih[g] + b_hh[g];
    for (int v = 0; v < V_; ++v) {
        float acc = bb;
#pragma unroll
        for (int e = 0; e < 32; ++e) acc = fmaf(emb_table[v * 32 + e], wemb[e], acc);
        ws[v * 256 + tidg] = acc;
    }
    float* wcatP = ws + V_ * 256;
#pragma unroll
    for (int k = 0; k < 64; ++k) wcatP[tidg * 128 + k] = W_ih[g * 96 + 32 + k];
#pragma unroll
    for (int k = 0; k < 64; ++k) wcatP[tidg * 128 + 64 + k] = W_hh[g * 64 + k];
}

// ---------------------------------------------------------------------------
// Main decoder: 1 block = 1 batch row, 256 threads, T=128 steps, 3 barriers/step.
//  - encS in LDS (round-2 structure; register-staging enc gets rematerialized
//    by the allocator into per-step global loads — round-3 regression).
//  - xbuf[2][128] = [h(64) | ctx(64)] fp16, double-buffered: b128 LDS reads.
//  - softmax denominator folded into P2's reduce (no P1 shuffle tree).
//  - P5 logits deferred one step, overlapped with P1 in Phase A.
//  - gate·h half-dot computed in Phase A (shares h loads with P1); P3 after
//    BB is only the ctx half + LSTM.
// ---------------------------------------------------------------------------
__global__ __launch_bounds__(256, 3) void decoder_kernel(
    const int* __restrict__ y, const float* __restrict__ h0,
    const float* __restrict__ c0, const float* __restrict__ enc,
    const float* __restrict__ fc_W, const float* __restrict__ fc_b,
    const float* __restrict__ ws, float* __restrict__ out)
{
    __shared__ uint2 encS[S_ * 16];                   // 32 KB, fp16 quads, swizzled
    __shared__ float4 attnP[16 * 17];                 // padded e-values (4.25 KB)
    __shared__ __align__(16) _Float16 xbuf[2][128];   // [h | ctx] double-buffered
    __shared__ float red[128];                        // logits reduction
    __shared__ int yrow[T_];

    const int tid = threadIdx.x;
    const int b = blockIdx.x;
    const int wid = tid >> 6;
    const int lane = tid & 63;

    // --- gate row registers (permuted ownership: quad lane qg, hidden jg) ---
    const int qg = lane & 3;
    const int jg = wid * 16 + (lane >> 2);
    const float* wcatP = ws + V_ * 256;
    uint2 wh[32];                                     // 128 fp16 weights = 64 VGPRs
    {
        const float4* wrow = (const float4*)(wcatP + tid * 128);
#pragma unroll
        for (int k = 0; k < 32; ++k) {
            float4 wv = wrow[k];
            wh[k].x = packh(wv.x, wv.y);
            wh[k].y = packh(wv.z, wv.w);
        }
    }

    // --- fc registers: thread (v = tid&31, jj = tid>>5) covers 16 k's ---
    const int v = tid & 31;
    const int jj = tid >> 5;
    uint2 fcwh[4];
    float fcb = 0.f;
    if (v < V_) {
#pragma unroll
        for (int k = 0; k < 4; ++k) {
            float4 wv = ((const float4*)(fc_W + v * 128 + jj * 16))[k];
            fcwh[k].x = packh(wv.x, wv.y);
            fcwh[k].y = packh(wv.z, wv.w);
        }
        fcb = fc_b[v];
    } else {
#pragma unroll
        for (int k = 0; k < 4; ++k) { fcwh[k].x = 0u; fcwh[k].y = 0u; }
    }

    // --- stage enc row into LDS (fp16, swizzled), init h/c/y ---
    {
        const float4* encg = (const float4*)(enc + (size_t)b * S_ * 64);
#pragma unroll
        for (int i = 0; i < 16; ++i) {
            int f4 = i * 256 + tid;
            int s = f4 >> 4, h4 = f4 & 15;
            float4 e = encg[f4];
            uint2 p;
            p.x = packh(e.x, e.y);
            p.y = packh(e.z, e.w);
            encS[enc_idx(s, h4)] = p;
        }
    }
    if (tid < 64) xbuf[0][tid] = (_Float16)h0[b * 64 + tid];
    float creg = c0[b * 64 + jg];                     // c state lives in a register
    if (tid < T_) yrow[tid] = y[b * T_ + tid];
    __syncthreads();

    // context-pass lane mapping
    const int hq = lane >> 4;           // 0..3
    const int sq = lane & 15;           // s-chunk of 16
    const int hqg = wid * 4 + hq;       // global h-quad 0..15
    const int tsw = tid + (tid >> 4);   // hoisted swizzle term for P1

    float* attnPf = (float*)attnP;
    float gh0, gh1, gh2, gh3;           // gate·h half, carried Phase A -> P3

    for (int t = 0; t < T_; ++t) {
        const int cur = t & 1, nxt = cur ^ 1;
        const float ge = ws[yrow[t] * 256 + tid];     // gate_embP, L1/L2-hot

        // ---- Phase A: P5 logits(t-1) + P1 scores(t) + gate·h half
        if (t) {
            // combined(t-1) = [h_new(t-1) | ctx(t-1)] = xbuf[cur][0:64] | xbuf[nxt][64:128]
            const _Float16* basep = &xbuf[jj < 4 ? cur : nxt][16 * jj];
            uint4 cA = *(const uint4*)basep;
            uint4 cB = *(const uint4*)(basep + 8);
            float a0 = dot2(fcwh[0].x, cA.x, 0.f);
            float a1 = dot2(fcwh[0].y, cA.y, 0.f);
            a0 = dot2(fcwh[1].x, cA.z, a0);
            a1 = dot2(fcwh[1].y, cA.w, a1);
            a0 = dot2(fcwh[2].x, cB.x, a0);
            a1 = dot2(fcwh[2].y, cB.y, a1);
            a0 = dot2(fcwh[3].x, cB.z, a0);
            a1 = dot2(fcwh[3].y, cB.w, a1);
            float acc = a0 + a1;
            acc += __shfl_xor(acc, 32);               // fold jj pairs
            if ((tid & 32) == 0) red[wid * 32 + v] = acc;
        }
        {
            float sc0 = 0.f, sc1 = 0.f, sc2 = 0.f, sc3 = 0.f;
            gh0 = 0.f; gh1 = 0.f; gh2 = 0.f; gh3 = 0.f;
#pragma unroll
            for (int i = 0; i < 8; ++i) {
                uint4 hv = *(const uint4*)&xbuf[cur][8 * i];  // quads 2i, 2i+1
                uint2 ea = encS[tid * 16 + ((2 * i + tsw) & 15)];
                uint2 eb = encS[tid * 16 + ((2 * i + 1 + tsw) & 15)];
                sc0 = dot2(ea.x, hv.x, sc0);
                sc1 = dot2(ea.y, hv.y, sc1);
                sc2 = dot2(eb.x, hv.z, sc2);
                sc3 = dot2(eb.y, hv.w, sc3);
                gh0 = dot2(wh[16 + 2 * i].x, hv.x, gh0);
                gh1 = dot2(wh[16 + 2 * i].y, hv.y, gh1);
                gh2 = dot2(wh[17 + 2 * i].x, hv.z, gh2);
                gh3 = dot2(wh[17 + 2 * i].y, hv.w, gh3);
            }
            float sc = (sc0 + sc1) + (sc2 + sc3);
            float ex = __expf(fminf(sc, 60.f));
            attnPf[(tid >> 4) * 68 + (tid & 15)] = ex;
        }
        __syncthreads();  // BA

        // out-write for step t-1 (red written this Phase A; next write is after BD)
        if (t && tid < V_) {
            float r = red[tid] + red[32 + tid] + red[64 + tid] + red[96 + tid] + fcb;
            out[((size_t)b * T_ + (t - 1)) * V_ + tid] = r;
        }

        // ---- P2: context + softmax denominator (5-component reduce over sq)
        {
            float4 acc = make_float4(0.f, 0.f, 0.f, 0.f);
            float es = 0.f;
#pragma unroll
            for (int k = 0; k < 4; ++k) {
                float4 a4 = attnP[sq * 17 + k];
                es += (a4.x + a4.y) + (a4.z + a4.w);
#pragma unroll
                for (int j2 = 0; j2 < 4; ++j2) {
                    int s = sq * 16 + 4 * k + j2;
                    uint2 e = encS[s * 16 + ((hqg + s + sq) & 15)];
                    h2_t e0 = __builtin_bit_cast(h2_t, e.x);
                    h2_t e1 = __builtin_bit_cast(h2_t, e.y);
                    float aw = (&a4.x)[j2];
                    acc.x = fmaf((float)e0.x, aw, acc.x);
                    acc.y = fmaf((float)e0.y, aw, acc.y);
                    acc.z = fmaf((float)e1.x, aw, acc.z);
                    acc.w = fmaf((float)e1.y, aw, acc.w);
                }
            }
#pragma unroll
            for (int off = 1; off <= 8; off <<= 1) {
                acc.x += __shfl_xor(acc.x, off);
                acc.y += __shfl_xor(acc.y, off);
                acc.z += __shfl_xor(acc.z, off);
                acc.w += __shfl_xor(acc.w, off);
                es    += __shfl_xor(es, off);
            }
            if (sq == 0) {
                const float inv = __builtin_amdgcn_rcpf(es);
                uint2 r;
                r.x = packh(acc.x * inv, acc.y * inv);
                r.y = packh(acc.z * inv, acc.w * inv);
                *(uint2*)&xbuf[cur][64 + 4 * hqg] = r;
            }
        }
        __syncthreads();  // BB

        // ---- P3: gate ctx-half dot + quad-shuffle LSTM
        {
            float g0 = ge, g1 = 0.f, g2 = 0.f, g3 = 0.f;
#pragma unroll
            for (int i = 0; i < 8; ++i) {
                uint4 xv = *(const uint4*)&xbuf[cur][64 + 8 * i];
                g0 = dot2(wh[2 * i].x, xv.x, g0);
                g1 = dot2(wh[2 * i].y, xv.y, g1);
                g2 = dot2(wh[2 * i + 1].x, xv.z, g2);
                g3 = dot2(wh[2 * i + 1].y, xv.w, g3);
            }
            float gacc = ((g0 + g1) + (g2 + g3)) + ((gh0 + gh1) + (gh2 + gh3));
            const float v1 = __shfl_xor(gacc, 1);
            const float v2 = __shfl_xor(gacc, 2);
            const float v3 = __shfl_xor(gacc, 3);
            // value of gate block p is [gacc,v1,v2,v3][p ^ qg]
            const bool b1 = qg & 1, b2 = qg & 2;
            const float gi = b2 ? (b1 ? v3 : v2) : (b1 ? v1 : gacc);
            const float gf = b2 ? (b1 ? v2 : v3) : (b1 ? gacc : v1);
            const float gg = b2 ? (b1 ? v1 : gacc) : (b1 ? v3 : v2);
            const float go = b2 ? (b1 ? gacc : v1) : (b1 ? v2 : v3);
            const float si = __builtin_amdgcn_rcpf(1.f + __expf(-gi));
            const float sf = __builtin_amdgcn_rcpf(1.f + __expf(-gf));
            const float so = __builtin_amdgcn_rcpf(1.f + __expf(-go));
            const float tg = 1.f - 2.f * __builtin_amdgcn_rcpf(__expf(2.f * gg) + 1.f);
            creg = sf * creg + si * tg;
            const float hn = so * (1.f - 2.f * __builtin_amdgcn_rcpf(__expf(2.f * creg) + 1.f));
            if (qg == 0) xbuf[nxt][jg] = (_Float16)hn;
        }
        __syncthreads();  // BD
    }

    // ---- tail: logits for step T-1. h_new(T-1) = xbuf[0][0:64], ctx(T-1) = xbuf[1][64:]
    {
        const _Float16* basep = &xbuf[jj < 4 ? 0 : 1][16 * jj];
        uint4 cA = *(const uint4*)basep;
        uint4 cB = *(const uint4*)(basep + 8);
        float a0 = dot2(fcwh[0].x, cA.x, 0.f);
        float a1 = dot2(fcwh[0].y, cA.y, 0.f);
        a0 = dot2(fcwh[1].x, cA.z, a0);
        a1 = dot2(fcwh[1].y, cA.w, a1);
        a0 = dot2(fcwh[2].x, cB.x, a0);
        a1 = dot2(fcwh[2].y, cB.y, a1);
        a0 = dot2(fcwh[3].x, cB.z, a0);
        a1 = dot2(fcwh[3].y, cB.w, a1);
        float acc = a0 + a1;
        acc += __shfl_xor(acc, 32);
        if ((tid & 32) == 0) red[wid * 32 + v] = acc;
    }
    __syncthreads();
    if (tid < V_) {
        float r = red[tid] + red[32 + tid] + red[64 + tid] + red[96 + tid] + fcb;
        out[((size_t)b * T_ + (T_ - 1)) * V_ + tid] = r;
    }
}

extern "C" void kernel_launch(void* const* d_in, const int* in_sizes, int n_in,
                              void* d_out, int out_size, void* d_ws, size_t ws_size,
                              hipStream_t stream)
{
    const int*   y    = (const int*)  d_in[0];
    const float* h0   = (const float*)d_in[1];
    const float* c0   = (const float*)d_in[2];
    const float* enc  = (const float*)d_in[3];
    const float* emb  = (const float*)d_in[4];
    const float* W_ih = (const float*)d_in[5];
    const float* W_hh = (const float*)d_in[6];
    const float* b_ih = (const float*)d_in[7];
    const float* b_hh = (const float*)d_in[8];
    const float* fc_W = (const float*)d_in[9];
    const float* fc_b = (const float*)d_in[10];
    float* ws  = (float*)d_ws;   // needs (29*256 + 256*128)*4 = 157 KB
    float* out = (float*)d_out;

    precompute_kernel<<<1, 256, 0, stream>>>(emb, W_ih, W_hh, b_ih, b_hh, ws);
    decoder_kernel<<<B_, 256, 0, stream>>>(y, h0, c0, enc, fc_W, fc_b, ws, out);
}

// Round 6
// 1266.240 us; speedup vs baseline: 3.7120x; 3.2189x over previous
//
#include <hip/hip_runtime.h>

#define B_ 2048
#define T_ 128
#define S_ 256
#define V_ 29

typedef _Float16 h2_t __attribute__((ext_vector_type(2)));
typedef __fp16 hh2 __attribute__((ext_vector_type(2)));

__device__ __forceinline__ unsigned packh(float a, float b) {
    h2_t p;
    p.x = (_Float16)a;
    p.y = (_Float16)b;
    return __builtin_bit_cast(unsigned, p);
}

// fp32 accumulate of a 2-term fp16 dot (v_dot2_f32_f16 on gfx950).
__device__ __forceinline__ float dot2(unsigned a, unsigned b, float c) {
#if __has_builtin(__builtin_amdgcn_fdot2)
    return __builtin_amdgcn_fdot2(__builtin_bit_cast(hh2, a),
                                  __builtin_bit_cast(hh2, b), c, false);
#else
    h2_t ah = __builtin_bit_cast(h2_t, a);
    h2_t bh = __builtin_bit_cast(h2_t, b);
    c = fmaf((float)ah.x, (float)bh.x, c);
    c = fmaf((float)ah.y, (float)bh.y, c);
    return c;
#endif
}

// Swizzled index for enc quad (s, h4) — quad is 4×fp16 = 8 B (uint2).
__device__ __forceinline__ int enc_idx(int s, int h4) {
    return s * 16 + ((h4 + s + (s >> 4)) & 15);
}

// ---------------------------------------------------------------------------
// Precompute (1 block, 256 threads). Thread g owns gate row g = q*64 + j.
// Consumer thread: tidg = (j>>4)*64 + (j&15)*4 + q (quad-of-lanes layout).
//   ws[0 .. 29*256)          gate_embP[v][tidg] = b_ih[g]+b_hh[g]+emb[v]·W_ih[g,0:32]
//   ws[29*256 .. +256*128)   wcatP[tidg][0:64]=W_ih[g][32:96] (ctx), [64:128]=W_hh[g] (h)
// ---------------------------------------------------------------------------
__global__ __launch_bounds__(256) void precompute_kernel(
    const float* __restrict__ emb_table, const float* __restrict__ W_ih,
    const float* __restrict__ W_hh, const float* __restrict__ b_ih,
    const float* __restrict__ b_hh, float* __restrict__ ws)
{
    const int g = threadIdx.x;
    const int q = g >> 6, j = g & 63;
    const int tidg = (j >> 4) * 64 + (j & 15) * 4 + q;

    float wemb[32];
#pragma unroll
    for (int e = 0; e < 32; ++e) wemb[e] = W_ih[g * 96 + e];
    const float bb = b_ih[g] + b_hh[g];
    for (int v = 0; v < V_; ++v) {
        float acc = bb;
#pragma unroll
        for (int e = 0; e < 32; ++e) acc = fmaf(emb_table[v * 32 + e], wemb[e], acc);
        ws[v * 256 + tidg] = acc;
    }
    float* wcatP = ws + V_ * 256;
#pragma unroll
    for (int k = 0; k < 64; ++k) wcatP[tidg * 128 + k] = W_ih[g * 96 + 32 + k];
#pragma unroll
    for (int k = 0; k < 64; ++k) wcatP[tidg * 128 + 64 + k] = W_hh[g * 64 + k];
}

// ---------------------------------------------------------------------------
// Main decoder: 1 block = 1 batch row, 256 threads, T=128 steps, 3 barriers/step.
// Round-2 structure (encS in LDS, separate ctxh/h2buf, wh only in P3) with:
//  - softmax denominator folded into P2's reduce (no P1 shuffle tree/redsum)
//  - P5 logits deferred one step into Phase A (4 -> 3 barriers/step)
// Both edits add only PHASE-LOCAL temps: no new loop-carried register state
// (rounds 3/5 showed the allocator rematerializes/spills loop-carried data
// into per-step HBM traffic when merged phases widen the live set).
// ---------------------------------------------------------------------------
__global__ __launch_bounds__(256, 3) void decoder_kernel(
    const int* __restrict__ y, const float* __restrict__ h0,
    const float* __restrict__ c0, const float* __restrict__ enc,
    const float* __restrict__ fc_W, const float* __restrict__ fc_b,
    const float* __restrict__ ws, float* __restrict__ out)
{
    __shared__ uint2 encS[S_ * 16];                   // 32 KB, fp16 quads, swizzled
    __shared__ float4 attnP[16 * 17];                 // padded e-values (4.25 KB)
    __shared__ __align__(16) _Float16 ctxh[64];       // context (fp16)
    __shared__ __align__(16) _Float16 h2buf[2][64];   // double-buffered h (fp16)
    __shared__ float red[128];                        // logits reduction
    __shared__ int yrow[T_];

    const int tid = threadIdx.x;
    const int b = blockIdx.x;
    const int wid = tid >> 6;
    const int lane = tid & 63;

    // --- gate row registers (permuted ownership: quad lane qg, hidden jg) ---
    const int qg = lane & 3;
    const int jg = wid * 16 + (lane >> 2);
    const float* wcatP = ws + V_ * 256;
    uint2 wh[32];                                     // 128 fp16 weights = 64 VGPRs
    {
        const float4* wrow = (const float4*)(wcatP + tid * 128);
#pragma unroll
        for (int k = 0; k < 32; ++k) {
            float4 wv = wrow[k];
            wh[k].x = packh(wv.x, wv.y);
            wh[k].y = packh(wv.z, wv.w);
        }
    }

    // --- fc registers: thread (v = tid&31, jj = tid>>5) covers 16 k's ---
    const int v = tid & 31;
    const int jj = tid >> 5;
    uint2 fcwh[4];
    float fcb = 0.f;
    if (v < V_) {
#pragma unroll
        for (int k = 0; k < 4; ++k) {
            float4 wv = ((const float4*)(fc_W + v * 128 + jj * 16))[k];
            fcwh[k].x = packh(wv.x, wv.y);
            fcwh[k].y = packh(wv.z, wv.w);
        }
        fcb = fc_b[v];
    } else {
#pragma unroll
        for (int k = 0; k < 4; ++k) { fcwh[k].x = 0u; fcwh[k].y = 0u; }
    }

    // --- stage enc row into LDS (fp16, swizzled), init h/c/y ---
    {
        const float4* encg = (const float4*)(enc + (size_t)b * S_ * 64);
#pragma unroll
        for (int i = 0; i < 16; ++i) {
            int f4 = i * 256 + tid;
            int s = f4 >> 4, h4 = f4 & 15;
            float4 e = encg[f4];
            uint2 p;
            p.x = packh(e.x, e.y);
            p.y = packh(e.z, e.w);
            encS[enc_idx(s, h4)] = p;
        }
    }
    if (tid < 64) h2buf[0][tid] = (_Float16)h0[b * 64 + tid];
    float creg = c0[b * 64 + jg];                     // c state lives in a register
    if (tid < T_) yrow[tid] = y[b * T_ + tid];
    __syncthreads();

    // context-pass lane mapping
    const int hq = lane >> 4;           // 0..3
    const int sq = lane & 15;           // s-chunk of 16
    const int hqg = wid * 4 + hq;       // global h-quad 0..15
    const int tsw = tid + (tid >> 4);   // hoisted swizzle term for P1

    float* attnPf = (float*)attnP;

    for (int t = 0; t < T_; ++t) {
        const int cur = t & 1, nxt = cur ^ 1;
        const float ge = ws[yrow[t] * 256 + tid];     // gate_embP, L1/L2-hot

        // ---- Phase A: P5 logits(t-1) overlapped with P1 scores(t)
        if (t) {
            // combined(t-1) = [h_new(t-1) | ctx(t-1)] = h2buf[cur] | ctxh
            const _Float16* basep = (jj < 4) ? &h2buf[cur][16 * jj] : &ctxh[16 * jj - 64];
            float a0 = 0.f, a1 = 0.f;
#pragma unroll
            for (int k = 0; k < 4; ++k) {
                uint2 c4 = *(const uint2*)(basep + 4 * k);
                a0 = dot2(fcwh[k].x, c4.x, a0);
                a1 = dot2(fcwh[k].y, c4.y, a1);
            }
            float acc = a0 + a1;
            acc += __shfl_xor(acc, 32);               // fold jj pairs
            if ((tid & 32) == 0) red[wid * 32 + v] = acc;
        }
        {
            float sc0 = 0.f, sc1 = 0.f, sc2 = 0.f, sc3 = 0.f;
#pragma unroll
            for (int i = 0; i < 16; i += 2) {
                uint2 ea = encS[tid * 16 + ((i + tsw) & 15)];
                uint2 eb = encS[tid * 16 + ((i + 1 + tsw) & 15)];
                uint2 ha = *(const uint2*)&h2buf[cur][4 * i];
                uint2 hb = *(const uint2*)&h2buf[cur][4 * i + 4];
                sc0 = dot2(ea.x, ha.x, sc0);
                sc1 = dot2(ea.y, ha.y, sc1);
                sc2 = dot2(eb.x, hb.x, sc2);
                sc3 = dot2(eb.y, hb.y, sc3);
            }
            float sc = (sc0 + sc1) + (sc2 + sc3);
            float ex = __expf(fminf(sc, 60.f));
            attnPf[(tid >> 4) * 68 + (tid & 15)] = ex;    // no shuffle tree: denom in P2
        }
        __syncthreads();  // BA

        // out-write for step t-1 (red stable until next Phase A, 2 barriers away)
        if (t && tid < V_) {
            float r = red[tid] + red[32 + tid] + red[64 + tid] + red[96 + tid] + fcb;
            out[((size_t)b * T_ + (t - 1)) * V_ + tid] = r;
        }

        // ---- P2: context + softmax denominator (5-component reduce over sq)
        {
            float4 acc = make_float4(0.f, 0.f, 0.f, 0.f);
            float es = 0.f;
#pragma unroll
            for (int k = 0; k < 4; ++k) {
                float4 a4 = attnP[sq * 17 + k];
                es += (a4.x + a4.y) + (a4.z + a4.w);
#pragma unroll
                for (int j2 = 0; j2 < 4; ++j2) {
                    int s = sq * 16 + 4 * k + j2;
                    uint2 e = encS[s * 16 + ((hqg + s + sq) & 15)];
                    h2_t e0 = __builtin_bit_cast(h2_t, e.x);
                    h2_t e1 = __builtin_bit_cast(h2_t, e.y);
                    float aw = (&a4.x)[j2];
                    acc.x = fmaf((float)e0.x, aw, acc.x);
                    acc.y = fmaf((float)e0.y, aw, acc.y);
                    acc.z = fmaf((float)e1.x, aw, acc.z);
                    acc.w = fmaf((float)e1.y, aw, acc.w);
                }
            }
#pragma unroll
            for (int off = 1; off <= 8; off <<= 1) {
                acc.x += __shfl_xor(acc.x, off);
                acc.y += __shfl_xor(acc.y, off);
                acc.z += __shfl_xor(acc.z, off);
                acc.w += __shfl_xor(acc.w, off);
                es    += __shfl_xor(es, off);
            }
            if (sq == 0) {
                const float inv = __builtin_amdgcn_rcpf(es);
                uint2 r;
                r.x = packh(acc.x * inv, acc.y * inv);
                r.y = packh(acc.z * inv, acc.w * inv);
                *(uint2*)&ctxh[4 * hqg] = r;
            }
        }
        __syncthreads();  // BB

        // ---- P3: gate dot (row qg*64+jg) + quad-shuffle LSTM
        {
            float g0 = ge, g1 = 0.f, g2 = 0.f, g3 = 0.f;
#pragma unroll
            for (int k = 0; k < 16; k += 2) {
                uint2 xa = *(const uint2*)&ctxh[4 * k];
                uint2 xb = *(const uint2*)&ctxh[4 * (k + 1)];
                g0 = dot2(wh[k].x, xa.x, g0);
                g1 = dot2(wh[k].y, xa.y, g1);
                g2 = dot2(wh[k + 1].x, xb.x, g2);
                g3 = dot2(wh[k + 1].y, xb.y, g3);
            }
#pragma unroll
            for (int k = 0; k < 16; k += 2) {
                uint2 xa = *(const uint2*)&h2buf[cur][4 * k];
                uint2 xb = *(const uint2*)&h2buf[cur][4 * (k + 1)];
                g0 = dot2(wh[16 + k].x, xa.x, g0);
                g1 = dot2(wh[16 + k].y, xa.y, g1);
                g2 = dot2(wh[17 + k].x, xb.x, g2);
                g3 = dot2(wh[17 + k].y, xb.y, g3);
            }
            float gacc = (g0 + g1) + (g2 + g3);
            const float v1 = __shfl_xor(gacc, 1);
            const float v2 = __shfl_xor(gacc, 2);
            const float v3 = __shfl_xor(gacc, 3);
            // value of gate block p is [gacc,v1,v2,v3][p ^ qg]
            const bool b1 = qg & 1, b2 = qg & 2;
            const float gi = b2 ? (b1 ? v3 : v2) : (b1 ? v1 : gacc);
            const float gf = b2 ? (b1 ? v2 : v3) : (b1 ? gacc : v1);
            const float gg = b2 ? (b1 ? v1 : gacc) : (b1 ? v3 : v2);
            const float go = b2 ? (b1 ? gacc : v1) : (b1 ? v2 : v3);
            const float si = __builtin_amdgcn_rcpf(1.f + __expf(-gi));
            const float sf = __builtin_amdgcn_rcpf(1.f + __expf(-gf));
            const float so = __builtin_amdgcn_rcpf(1.f + __expf(-go));
            const float tg = 1.f - 2.f * __builtin_amdgcn_rcpf(__expf(2.f * gg) + 1.f);
            creg = sf * creg + si * tg;
            const float hn = so * (1.f - 2.f * __builtin_amdgcn_rcpf(__expf(2.f * creg) + 1.f));
            if (qg == 0) h2buf[nxt][jg] = (_Float16)hn;
        }
        __syncthreads();  // BD
    }

    // ---- tail: logits for step T-1. h_new(T-1) = h2buf[T_&1 ^ 1] = h2buf[0]
    {
        const _Float16* basep = (jj < 4) ? &h2buf[0][16 * jj] : &ctxh[16 * jj - 64];
        float a0 = 0.f, a1 = 0.f;
#pragma unroll
        for (int k = 0; k < 4; ++k) {
            uint2 c4 = *(const uint2*)(basep + 4 * k);
            a0 = dot2(fcwh[k].x, c4.x, a0);
            a1 = dot2(fcwh[k].y, c4.y, a1);
        }
        float acc = a0 + a1;
        acc += __shfl_xor(acc, 32);
        if ((tid & 32) == 0) red[wid * 32 + v] = acc;
    }
    __syncthreads();
    if (tid < V_) {
        float r = red[tid] + red[32 + tid] + red[64 + tid] + red[96 + tid] + fcb;
        out[((size_t)b * T_ + (T_ - 1)) * V_ + tid] = r;
    }
}

extern "C" void kernel_launch(void* const* d_in, const int* in_sizes, int n_in,
                              void* d_out, int out_size, void* d_ws, size_t ws_size,
                              hipStream_t stream)
{
    const int*   y    = (const int*)  d_in[0];
    const float* h0   = (const float*)d_in[1];
    const float* c0   = (const float*)d_in[2];
    const float* enc  = (const float*)d_in[3];
    const float* emb  = (const float*)d_in[4];
    const float* W_ih = (const float*)d_in[5];
    const float* W_hh = (const float*)d_in[6];
    const float* b_ih = (const float*)d_in[7];
    const float* b_hh = (const float*)d_in[8];
    const float* fc_W = (const float*)d_in[9];
    const float* fc_b = (const float*)d_in[10];
    float* ws  = (float*)d_ws;   // needs (29*256 + 256*128)*4 = 157 KB
    float* out = (float*)d_out;

    precompute_kernel<<<1, 256, 0, stream>>>(emb, W_ih, W_hh, b_ih, b_hh, ws);
    decoder_kernel<<<B_, 256, 0, stream>>>(y, h0, c0, enc, fc_W, fc_b, ws, out);
}